// Round 2
// baseline (938.524 us; speedup 1.0000x reference)
//
#include <hip/hip_runtime.h>

typedef unsigned short u16;
typedef unsigned int u32;
typedef __attribute__((ext_vector_type(8))) short bf16x8;
typedef __attribute__((ext_vector_type(4))) float f32x4;

__device__ __forceinline__ u16 f2bf(float f) {
  u32 u = __float_as_uint(f);
  u += 0x7fffu + ((u >> 16) & 1u);
  return (u16)(u >> 16);
}
__device__ __forceinline__ float bf2f(short h) {
  return __uint_as_float(((u32)(u16)h) << 16);
}

// ---------------- convert x: f32 -> bf16 (straight) ----------------
__global__ __launch_bounds__(256) void k_cvt(const float* __restrict__ in, u16* __restrict__ out, int n) {
  int idx = (blockIdx.x * 256 + threadIdx.x) * 8;
  if (idx >= n) return;
  float4 a = *(const float4*)&in[idx];
  float4 b = *(const float4*)&in[idx + 4];
  union { u16 h[8]; uint4 v; } t;
  t.h[0] = f2bf(a.x); t.h[1] = f2bf(a.y); t.h[2] = f2bf(a.z); t.h[3] = f2bf(a.w);
  t.h[4] = f2bf(b.x); t.h[5] = f2bf(b.y); t.h[6] = f2bf(b.z); t.h[7] = f2bf(b.w);
  *(uint4*)&out[idx] = t.v;
}

// ---------------- transpose+convert: out[c][r] = bf16(in[r][c]); R,C multiples of 64 ----------------
__global__ __launch_bounds__(256) void k_tcvt(const float* __restrict__ in, u16* __restrict__ out, int R, int C) {
  __shared__ u16 T[64 * 72];
  int t = threadIdx.x;
  int r0 = blockIdx.y * 64, c0 = blockIdx.x * 64;
  for (int i = 0; i < 4; i++) {
    int cc = i * 256 + t; int r = cc >> 4; int s = cc & 15;
    float4 v = *(const float4*)&in[(size_t)(r0 + r) * C + c0 + s * 4];
    T[r * 72 + s * 4 + 0] = f2bf(v.x);
    T[r * 72 + s * 4 + 1] = f2bf(v.y);
    T[r * 72 + s * 4 + 2] = f2bf(v.z);
    T[r * 72 + s * 4 + 3] = f2bf(v.w);
  }
  __syncthreads();
  for (int i = 0; i < 2; i++) {
    int cc = i * 256 + t; int c = cc >> 3; int s2 = cc & 7;
    union { u16 h[8]; uint4 v; } tmp;
    for (int e = 0; e < 8; e++) tmp.h[e] = T[(s2 * 8 + e) * 72 + c];
    *(uint4*)&out[(size_t)(c0 + c) * R + r0 + s2 * 8] = tmp.v;
  }
}

// ---------------- transpose v-part of qkv (bf16) into Vt[512][8192] ----------------
__global__ __launch_bounds__(256) void k_tv(const u16* __restrict__ qkv, u16* __restrict__ vt) {
  __shared__ u16 T[64 * 72];
  int t = threadIdx.x;
  int r0 = blockIdx.y * 64;   // token rows
  int d0 = blockIdx.x * 64;   // head-dim rows of vt
  for (int i = 0; i < 2; i++) {
    int cc = i * 256 + t; int r = cc >> 3; int s = cc & 7;
    *(uint4*)&T[r * 72 + s * 8] = *(const uint4*)&qkv[(size_t)(r0 + r) * 1536 + 1024 + d0 + s * 8];
  }
  __syncthreads();
  for (int i = 0; i < 2; i++) {
    int cc = i * 256 + t; int d = cc >> 3; int s2 = cc & 7;
    union { u16 h[8]; uint4 v; } tmp;
    for (int e = 0; e < 8; e++) tmp.h[e] = T[(s2 * 8 + e) * 72 + d];
    *(uint4*)&vt[(size_t)(d0 + d) * 8192 + r0 + s2 * 8] = tmp.v;
  }
}

// ---------------- GEMM: C[M,N] = A[M,K] @ Bt[N,K]^T + bias; bf16 in, bf16 or f32 out ----------------
__global__ __launch_bounds__(256) void k_gemm(const u16* __restrict__ A, const u16* __restrict__ Bt,
                                              const float* __restrict__ bias,
                                              u16* __restrict__ Cb, float* __restrict__ Cf,
                                              int M, int N, int K) {
  __shared__ u16 As[128 * 64];
  __shared__ u16 Bs[128 * 64];
  const int t = threadIdx.x;
  const int l = t & 63, w = t >> 6;
  const int l16 = l & 15, g = l >> 4;
  const int m0 = blockIdx.y * 128, n0 = blockIdx.x * 128;
  const int wr = (w >> 1) * 64, wc = (w & 1) * 64;
  f32x4 acc[4][4] = {};
  for (int kk = 0; kk < K; kk += 64) {
    __syncthreads();
#pragma unroll
    for (int i = 0; i < 4; i++) {
      int c = i * 256 + t;
      int r = c >> 3, g2 = c & 7;
      int sg = g2 ^ (r & 7);   // pre-swizzled global source, linear LDS dest
      __builtin_amdgcn_global_load_lds(
          (const __attribute__((address_space(1))) u32*)(A + (size_t)(m0 + r) * K + kk + sg * 8),
          (__attribute__((address_space(3))) u32*)&As[c * 8], 16, 0, 0);
      __builtin_amdgcn_global_load_lds(
          (const __attribute__((address_space(1))) u32*)(Bt + (size_t)(n0 + r) * K + kk + sg * 8),
          (__attribute__((address_space(3))) u32*)&Bs[c * 8], 16, 0, 0);
    }
    __syncthreads();
#pragma unroll
    for (int kh = 0; kh < 2; kh++) {
      bf16x8 a[4];
#pragma unroll
      for (int mi = 0; mi < 4; mi++) {
        int row = wr + 16 * mi + l16;
        int s = (kh * 4 + g) ^ (row & 7);
        a[mi] = *(const bf16x8*)&As[row * 64 + s * 8];
      }
#pragma unroll
      for (int ni = 0; ni < 4; ni++) {
        int row = wc + 16 * ni + l16;
        int s = (kh * 4 + g) ^ (row & 7);
        bf16x8 b = *(const bf16x8*)&Bs[row * 64 + s * 8];
#pragma unroll
        for (int mi = 0; mi < 4; mi++)
          acc[mi][ni] = __builtin_amdgcn_mfma_f32_16x16x32_bf16(a[mi], b, acc[mi][ni], 0, 0, 0);
      }
    }
  }
#pragma unroll
  for (int ni = 0; ni < 4; ni++) {
    int col = n0 + wc + 16 * ni + l16;
    float bv = bias[col];
#pragma unroll
    for (int mi = 0; mi < 4; mi++) {
      int row0 = m0 + wr + 16 * mi + 4 * g;
#pragma unroll
      for (int r = 0; r < 4; r++) {
        float v = acc[mi][ni][r] + bv;
        if (Cf) Cf[(size_t)(row0 + r) * N + col] = v;
        else    Cb[(size_t)(row0 + r) * N + col] = f2bf(v);
      }
    }
  }
}

// ---------------- flash attention partials: causal, D=512, BQ=32, BK=32, 4 waves ----------------
// Block (c, qi): KV tiles [c*CT, min((c+1)*CT, qi+1)). Writes UNNORMALIZED O + (m,l) per slot.
// slot(qi,c) = qi + CT*k*(k-1)/2 + (qi%CT)*k + c, k = qi/CT  (prefix sum of ceil((q'+1)/CT))
__global__ __launch_bounds__(256) void k_flash2(const u16* __restrict__ qkv, const u16* __restrict__ vt,
                                                u16* __restrict__ Op, float* __restrict__ mp,
                                                float* __restrict__ lp, int CT) {
  __shared__ u16 Ks[32 * 512];    // linear layout (global_load_lds), XOR-swizzled 16B units
  __shared__ u16 Ps[32 * 40];
  __shared__ float redm[2][32];
  __shared__ float reds[2][32];
  const int qi = blockIdx.y, c = blockIdx.x;
  const int k0 = qi / CT;
  if (c > k0) return;                 // nch = k0+1
  const int slot = qi + CT * k0 * (k0 - 1) / 2 + (qi % CT) * k0 + c;
  const int jlo = c * CT;
  const int jhi = min((c + 1) * CT, qi + 1);
  const int t = threadIdx.x;
  const int l = t & 63, w = t >> 6;
  const int l16 = l & 15, g = l >> 4;
  const int q0 = qi * 32;
  const int wrow = (w >> 1) * 16, wcol = (w & 1) * 16;
  const int town = w >> 1;
  const float scale = 0.044194173824159216f;  // 1/sqrt(512)

  bf16x8 qa[16];
#pragma unroll
  for (int ks = 0; ks < 16; ks++)
    qa[ks] = *(const bf16x8*)&qkv[(size_t)(q0 + wrow + l16) * 1536 + ks * 32 + g * 8];

  f32x4 acc[2][8] = {};
  float m_st[2][4], l_st[2][4];
#pragma unroll
  for (int tt = 0; tt < 2; tt++)
#pragma unroll
    for (int r = 0; r < 4; r++) { m_st[tt][r] = -1.0e30f; l_st[tt][r] = 0.f; }

  for (int j0 = jlo; j0 < jhi; j0++) {
    __syncthreads();                  // prev iteration's Ks/Ps readers done
#pragma unroll
    for (int i = 0; i < 8; i++) {     // stage K tile (32 x 512) async, swizzled source
      int cc = i * 256 + t;           // 16B-unit id, 0..2047
      int r = cc >> 6, u = cc & 63;
      int su = (u & 56) | ((u & 7) ^ (r & 7));
      __builtin_amdgcn_global_load_lds(
          (const __attribute__((address_space(1))) u32*)(qkv + (size_t)(j0 * 32 + r) * 1536 + 512 + su * 8),
          (__attribute__((address_space(3))) u32*)&Ks[cc * 8], 16, 0, 0);
    }
    __syncthreads();                  // staging complete (vmcnt drained before barrier)

    // QK^T: 16x16 quadrant per wave, K-dim 512
    f32x4 S = {0.f, 0.f, 0.f, 0.f};
#pragma unroll
    for (int ks = 0; ks < 16; ks++) {
      int u = ks * 4 + g;
      int su = (u & 56) | ((u & 7) ^ (l16 & 7));
      bf16x8 b = *(const bf16x8*)&Ks[(wcol + l16) * 512 + su * 8];
      S = __builtin_amdgcn_mfma_f32_16x16x32_bf16(qa[ks], b, S, 0, 0, 0);
    }
    float sv[4];
#pragma unroll
    for (int r = 0; r < 4; r++) {
      float s = S[r] * scale;
      if (j0 == qi) {
        int col = j0 * 32 + wcol + l16;
        int row = q0 + wrow + 4 * g + r;
        if (col > row) s = -1e10f;
      }
      sv[r] = s;
      float v = s;
#pragma unroll
      for (int off = 1; off < 16; off <<= 1) v = fmaxf(v, __shfl_xor(v, off));
      if (l16 == 0) redm[w & 1][wrow + 4 * g + r] = v;  // partial row max (this col half)
    }
    __syncthreads();

    float sc[2][4];
#pragma unroll
    for (int tt = 0; tt < 2; tt++)
#pragma unroll
      for (int r = 0; r < 4; r++) {
        int row = 16 * tt + 4 * g + r;
        float mx = fmaxf(redm[0][row], redm[1][row]);
        float mnew = fmaxf(m_st[tt][r], mx);
        sc[tt][r] = __expf(m_st[tt][r] - mnew);
        m_st[tt][r] = mnew;
      }
#pragma unroll
    for (int r = 0; r < 4; r++) {
      float p = __expf(sv[r] - m_st[town][r]);
      Ps[(wrow + 4 * g + r) * 40 + wcol + l16] = f2bf(p);
      float v = p;
#pragma unroll
      for (int off = 1; off < 16; off <<= 1) v += __shfl_xor(v, off);
      if (l16 == 0) reds[w & 1][wrow + 4 * g + r] = v;  // partial row sum
    }
#pragma unroll
    for (int tt = 0; tt < 2; tt++) {
#pragma unroll
      for (int cc2 = 0; cc2 < 8; cc2++)
#pragma unroll
        for (int r = 0; r < 4; r++)
          acc[tt][cc2][r] *= sc[tt][r];
#pragma unroll
      for (int r = 0; r < 4; r++) l_st[tt][r] *= sc[tt][r];
    }
    __syncthreads();
#pragma unroll
    for (int tt = 0; tt < 2; tt++)
#pragma unroll
      for (int r = 0; r < 4; r++) {
        int row = 16 * tt + 4 * g + r;
        l_st[tt][r] += reds[0][row] + reds[1][row];
      }
    // PV: V B-frags straight from global (contiguous 16B in vt[d][kv]); P from LDS
    bf16x8 pa0 = *(const bf16x8*)&Ps[(l16) * 40 + g * 8];
    bf16x8 pa1 = *(const bf16x8*)&Ps[(16 + l16) * 40 + g * 8];
#pragma unroll
    for (int cc2 = 0; cc2 < 8; cc2++) {
      bf16x8 vb = *(const bf16x8*)&vt[(size_t)(128 * w + 16 * cc2 + l16) * 8192 + j0 * 32 + g * 8];
      acc[0][cc2] = __builtin_amdgcn_mfma_f32_16x16x32_bf16(pa0, vb, acc[0][cc2], 0, 0, 0);
      acc[1][cc2] = __builtin_amdgcn_mfma_f32_16x16x32_bf16(pa1, vb, acc[1][cc2], 0, 0, 0);
    }
  }
  // epilogue: unnormalized partials
#pragma unroll
  for (int tt = 0; tt < 2; tt++)
#pragma unroll
    for (int cc2 = 0; cc2 < 8; cc2++)
#pragma unroll
      for (int r = 0; r < 4; r++) {
        int rowl = 16 * tt + 4 * g + r;
        int col = 128 * w + 16 * cc2 + l16;
        Op[(size_t)slot * 16384 + rowl * 512 + col] = f2bf(acc[tt][cc2][r]);
      }
  if (w == 0 && l16 == 0) {
#pragma unroll
    for (int tt = 0; tt < 2; tt++)
#pragma unroll
      for (int r = 0; r < 4; r++) {
        int rowl = 16 * tt + 4 * g + r;
        mp[slot * 32 + rowl] = m_st[tt][r];
        lp[slot * 32 + rowl] = l_st[tt][r];
      }
  }
}

// ---------------- combine partials -> normalized O (bf16) ----------------
__global__ __launch_bounds__(256) void k_comb(const u16* __restrict__ Op, const float* __restrict__ mp,
                                              const float* __restrict__ lp, u16* __restrict__ Ob, int CT) {
  const int qi = blockIdx.x;
  const int k0 = qi / CT;
  const int nch = k0 + 1;
  const int base = qi + CT * k0 * (k0 - 1) / 2 + (qi % CT) * k0;
  const int t = threadIdx.x;
  const int row = t >> 3, cg = t & 7;
  float M = -1.0e30f;
#pragma unroll 4
  for (int c = 0; c < 4; c++)
    if (c < nch) M = fmaxf(M, mp[(base + c) * 32 + row]);
  float wgt[4] = {0.f, 0.f, 0.f, 0.f};
  float L = 0.f;
#pragma unroll 4
  for (int c = 0; c < 4; c++)
    if (c < nch) {
      float wv = __expf(mp[(base + c) * 32 + row] - M);
      wgt[c] = wv;
      L += lp[(base + c) * 32 + row] * wv;
    }
  float inv = 1.0f / L;
#pragma unroll
  for (int gsub = 0; gsub < 8; gsub++) {
    int d0 = cg * 64 + gsub * 8;
    float o[8] = {};
#pragma unroll 4
    for (int c = 0; c < 4; c++)
      if (c < nch) {
        bf16x8 v = *(const bf16x8*)&Op[(size_t)(base + c) * 16384 + row * 512 + d0];
#pragma unroll
        for (int e = 0; e < 8; e++) o[e] += wgt[c] * bf2f(v[e]);
      }
    union { u16 h[8]; uint4 u; } pk;
#pragma unroll
    for (int e = 0; e < 8; e++) pk.h[e] = f2bf(o[e] * inv);
    *(uint4*)&Ob[(size_t)(qi * 32 + row) * 512 + d0] = pk.u;
  }
}

extern "C" void kernel_launch(void* const* d_in, const int* in_sizes, int n_in,
                              void* d_out, int out_size, void* d_ws, size_t ws_size,
                              hipStream_t stream) {
  const float* x     = (const float*)d_in[0];
  const float* w_qkv = (const float*)d_in[1];
  const float* b_qkv = (const float*)d_in[2];
  const float* w_out = (const float*)d_in[3];
  const float* b_out = (const float*)d_in[4];
  float* out = (float*)d_out;
  char* ws = (char*)d_ws;
  // base layout (60 MB)
  u16* xb    = (u16*)(ws);               // [8192][1024] bf16   (dead after gemm1)
  u16* wqkvT = (u16*)(ws + 16777216);    // [1536][1024] bf16   (dead after gemm1)
  u16* woutT = (u16*)(ws + 19922944);    // [1024][512]  bf16
  u16* qkv   = (u16*)(ws + 20971520);    // [8192][1536] bf16
  u16* vt    = (u16*)(ws + 46137344);    // [512][8192]  bf16
  u16* Ob    = (u16*)(ws + 54525952);    // [8192][512]  bf16   (ends 62914560)

  // flash partial layout: A (chunk=2048, 640 slots) if ws allows, else B (chunk=4096,
  // 384 slots overlaid on dead xb region)
  int CT, maxc;
  u16* Opart; float* mpart; float* lpart;
  if (ws_size >= (size_t)84049920) {
    CT = 64; maxc = 4;
    Opart = (u16*)(ws + 62914560);       // 640*32*512*2 = 20971520
    mpart = (float*)(ws + 83886080);     // 640*32*4 = 81920
    lpart = (float*)(ws + 83886080 + 81920);
  } else {
    CT = 128; maxc = 2;
    Opart = (u16*)(ws);                  // 384*32*512*2 = 12582912  (xb is dead by then)
    mpart = (float*)(ws + 12582912);     // 384*32*4 = 49152
    lpart = (float*)(ws + 12582912 + 49152);
  }

  k_cvt<<<4096, 256, 0, stream>>>(x, xb, 8192 * 1024);
  k_tcvt<<<dim3(24, 16), 256, 0, stream>>>(w_qkv, wqkvT, 1024, 1536);
  k_tcvt<<<dim3(16, 8), 256, 0, stream>>>(w_out, woutT, 512, 1024);
  k_gemm<<<dim3(12, 64), 256, 0, stream>>>(xb, wqkvT, b_qkv, qkv, nullptr, 8192, 1536, 1024);
  k_tv<<<dim3(8, 128), 256, 0, stream>>>(qkv, vt);
  k_flash2<<<dim3(maxc, 256), 256, 0, stream>>>(qkv, vt, Opart, mpart, lpart, CT);
  k_comb<<<256, 256, 0, stream>>>(Opart, mpart, lpart, Ob, CT);
  k_gemm<<<dim3(8, 64), 256, 0, stream>>>(Ob, woutT, b_out, nullptr, out, 8192, 1024, 512);
}

// Round 3
// 909.238 us; speedup vs baseline: 1.0322x; 1.0322x over previous
//
#include <hip/hip_runtime.h>

typedef unsigned short u16;
typedef unsigned int u32;
typedef __attribute__((ext_vector_type(8))) short bf16x8;
typedef __attribute__((ext_vector_type(4))) float f32x4;

__device__ __forceinline__ u16 f2bf(float f) {
  u32 u = __float_as_uint(f);
  u += 0x7fffu + ((u >> 16) & 1u);
  return (u16)(u >> 16);
}
__device__ __forceinline__ float bf2f(short h) {
  return __uint_as_float(((u32)(u16)h) << 16);
}

// ---------------- convert x: f32 -> bf16 (straight) ----------------
__global__ __launch_bounds__(256) void k_cvt(const float* __restrict__ in, u16* __restrict__ out, int n) {
  int idx = (blockIdx.x * 256 + threadIdx.x) * 8;
  if (idx >= n) return;
  float4 a = *(const float4*)&in[idx];
  float4 b = *(const float4*)&in[idx + 4];
  union { u16 h[8]; uint4 v; } t;
  t.h[0] = f2bf(a.x); t.h[1] = f2bf(a.y); t.h[2] = f2bf(a.z); t.h[3] = f2bf(a.w);
  t.h[4] = f2bf(b.x); t.h[5] = f2bf(b.y); t.h[6] = f2bf(b.z); t.h[7] = f2bf(b.w);
  *(uint4*)&out[idx] = t.v;
}

// ---------------- transpose+convert: out[c][r] = bf16(in[r][c]); R,C multiples of 64 ----------------
__global__ __launch_bounds__(256) void k_tcvt(const float* __restrict__ in, u16* __restrict__ out, int R, int C) {
  __shared__ u16 T[64 * 72];
  int t = threadIdx.x;
  int r0 = blockIdx.y * 64, c0 = blockIdx.x * 64;
  for (int i = 0; i < 4; i++) {
    int cc = i * 256 + t; int r = cc >> 4; int s = cc & 15;
    float4 v = *(const float4*)&in[(size_t)(r0 + r) * C + c0 + s * 4];
    T[r * 72 + s * 4 + 0] = f2bf(v.x);
    T[r * 72 + s * 4 + 1] = f2bf(v.y);
    T[r * 72 + s * 4 + 2] = f2bf(v.z);
    T[r * 72 + s * 4 + 3] = f2bf(v.w);
  }
  __syncthreads();
  for (int i = 0; i < 2; i++) {
    int cc = i * 256 + t; int c = cc >> 3; int s2 = cc & 7;
    union { u16 h[8]; uint4 v; } tmp;
    for (int e = 0; e < 8; e++) tmp.h[e] = T[(s2 * 8 + e) * 72 + c];
    *(uint4*)&out[(size_t)(c0 + c) * R + r0 + s2 * 8] = tmp.v;
  }
}

// ---------------- transpose v-part of qkv (bf16) into Vt[512][8192] ----------------
__global__ __launch_bounds__(256) void k_tv(const u16* __restrict__ qkv, u16* __restrict__ vt) {
  __shared__ u16 T[64 * 72];
  int t = threadIdx.x;
  int r0 = blockIdx.y * 64;   // token rows
  int d0 = blockIdx.x * 64;   // head-dim rows of vt
  for (int i = 0; i < 2; i++) {
    int cc = i * 256 + t; int r = cc >> 3; int s = cc & 7;
    *(uint4*)&T[r * 72 + s * 8] = *(const uint4*)&qkv[(size_t)(r0 + r) * 1536 + 1024 + d0 + s * 8];
  }
  __syncthreads();
  for (int i = 0; i < 2; i++) {
    int cc = i * 256 + t; int d = cc >> 3; int s2 = cc & 7;
    union { u16 h[8]; uint4 v; } tmp;
    for (int e = 0; e < 8; e++) tmp.h[e] = T[(s2 * 8 + e) * 72 + d];
    *(uint4*)&vt[(size_t)(d0 + d) * 8192 + r0 + s2 * 8] = tmp.v;
  }
}

// ---------------- GEMM: C[M,N] = A[M,K] @ Bt[N,K]^T + bias; bf16 in, bf16 or f32 out ----------------
__global__ __launch_bounds__(256) void k_gemm(const u16* __restrict__ A, const u16* __restrict__ Bt,
                                              const float* __restrict__ bias,
                                              u16* __restrict__ Cb, float* __restrict__ Cf,
                                              int M, int N, int K) {
  __shared__ u16 As[128 * 64];
  __shared__ u16 Bs[128 * 64];
  const int t = threadIdx.x;
  const int l = t & 63, w = t >> 6;
  const int l16 = l & 15, g = l >> 4;
  const int m0 = blockIdx.y * 128, n0 = blockIdx.x * 128;
  const int wr = (w >> 1) * 64, wc = (w & 1) * 64;
  f32x4 acc[4][4] = {};
  for (int kk = 0; kk < K; kk += 64) {
    __syncthreads();
#pragma unroll
    for (int i = 0; i < 4; i++) {
      int c = i * 256 + t;
      int r = c >> 3, g2 = c & 7;
      int sg = g2 ^ (r & 7);   // pre-swizzled global source, linear LDS dest
      __builtin_amdgcn_global_load_lds(
          (const __attribute__((address_space(1))) u32*)(A + (size_t)(m0 + r) * K + kk + sg * 8),
          (__attribute__((address_space(3))) u32*)&As[c * 8], 16, 0, 0);
      __builtin_amdgcn_global_load_lds(
          (const __attribute__((address_space(1))) u32*)(Bt + (size_t)(n0 + r) * K + kk + sg * 8),
          (__attribute__((address_space(3))) u32*)&Bs[c * 8], 16, 0, 0);
    }
    __syncthreads();
#pragma unroll
    for (int kh = 0; kh < 2; kh++) {
      bf16x8 a[4];
#pragma unroll
      for (int mi = 0; mi < 4; mi++) {
        int row = wr + 16 * mi + l16;
        int s = (kh * 4 + g) ^ (row & 7);
        a[mi] = *(const bf16x8*)&As[row * 64 + s * 8];
      }
#pragma unroll
      for (int ni = 0; ni < 4; ni++) {
        int row = wc + 16 * ni + l16;
        int s = (kh * 4 + g) ^ (row & 7);
        bf16x8 b = *(const bf16x8*)&Bs[row * 64 + s * 8];
#pragma unroll
        for (int mi = 0; mi < 4; mi++)
          acc[mi][ni] = __builtin_amdgcn_mfma_f32_16x16x32_bf16(a[mi], b, acc[mi][ni], 0, 0, 0);
      }
    }
  }
#pragma unroll
  for (int ni = 0; ni < 4; ni++) {
    int col = n0 + wc + 16 * ni + l16;
    float bv = bias[col];
#pragma unroll
    for (int mi = 0; mi < 4; mi++) {
      int row0 = m0 + wr + 16 * mi + 4 * g;
#pragma unroll
      for (int r = 0; r < 4; r++) {
        float v = acc[mi][ni][r] + bv;
        if (Cf) Cf[(size_t)(row0 + r) * N + col] = v;
        else    Cb[(size_t)(row0 + r) * N + col] = f2bf(v);
      }
    }
  }
}

// ---------------- flash attention partials v3: KB=128 rounds, double-buffered K ----------------
// Block (c, qi): KV tiles [c*CT, min((c+1)*CT, qi+1)), tiles are 32 tokens, CT multiple of 4.
// Writes UNNORMALIZED O + (m,l) per slot; slot formula as before.
__global__ __launch_bounds__(256, 2) void k_flash3(const u16* __restrict__ qkv, const u16* __restrict__ vt,
                                                   u16* __restrict__ Op, float* __restrict__ mp,
                                                   float* __restrict__ lp, int CT) {
  __shared__ u16 Ks[2][32 * 512];  // ring of 2 K tiles, linear dest, XOR-swizzled source
  __shared__ u16 Ps[32 * 136];     // P for 128 cols, padded stride
  __shared__ float redm[2][32];
  __shared__ float reds[2][32];
  const int qi = blockIdx.y, c = blockIdx.x;
  const int k0 = qi / CT;
  if (c > k0) return;
  const int slot = qi + CT * k0 * (k0 - 1) / 2 + (qi % CT) * k0 + c;
  const int jlo = c * CT;
  const int jhi = min((c + 1) * CT, qi + 1);
  const int t = threadIdx.x;
  const int l = t & 63, w = t >> 6;
  const int l16 = l & 15, g = l >> 4;
  const int q0 = qi * 32;
  const int wrow = (w >> 1) * 16, wcol = (w & 1) * 16;
  const int town = w >> 1;
  const float scale = 0.044194173824159216f;  // 1/sqrt(512)

  auto stage = [&](int j) {
#pragma unroll
    for (int i = 0; i < 8; i++) {
      int cc = i * 256 + t;           // 16B unit 0..2047
      int r = cc >> 6, u = cc & 63;
      int su = (u & 56) | ((u & 7) ^ (r & 7));
      __builtin_amdgcn_global_load_lds(
          (const __attribute__((address_space(1))) u32*)(qkv + (size_t)(j * 32 + r) * 1536 + 512 + su * 8),
          (__attribute__((address_space(3))) u32*)&Ks[j & 1][cc * 8], 16, 0, 0);
    }
  };

  // hoist Q fragments (64 VGPR)
  bf16x8 qa[16];
#pragma unroll
  for (int ks = 0; ks < 16; ks++)
    qa[ks] = *(const bf16x8*)&qkv[(size_t)(q0 + wrow + l16) * 1536 + ks * 32 + g * 8];

  f32x4 acc[2][8] = {};
  float m_st[2][4], l_st[2][4];
#pragma unroll
  for (int tt = 0; tt < 2; tt++)
#pragma unroll
    for (int r = 0; r < 4; r++) { m_st[tt][r] = -1.0e30f; l_st[tt][r] = 0.f; }

  stage(jlo);
  __syncthreads();

  for (int j0 = jlo; j0 < jhi; j0 += 4) {
    const int ns = min(4, jhi - j0);
    float sv[4][4];
#pragma unroll
    for (int s = 0; s < 4; s++)
#pragma unroll
      for (int r = 0; r < 4; r++) sv[s][r] = -3.0e38f;

    // ---- QK phase: up to 4 sub-tiles, prefetch next tile before compute ----
#pragma unroll
    for (int s = 0; s < 4; s++) {
      if (s < ns) {
        if (s < 3 && j0 + s + 1 < jhi) stage(j0 + s + 1);
        const u16* kb = &Ks[(j0 + s) & 1][0];
        f32x4 Sa = {0.f, 0.f, 0.f, 0.f}, Sb = {0.f, 0.f, 0.f, 0.f};
#pragma unroll
        for (int kp = 0; kp < 8; kp++) {
          int ka = 2 * kp, kbn = 2 * kp + 1;
          int ua = ka * 4 + g, ub = kbn * 4 + g;
          int sua = (ua & 56) | ((ua & 7) ^ (l16 & 7));
          int sub = (ub & 56) | ((ub & 7) ^ (l16 & 7));
          bf16x8 ba = *(const bf16x8*)&kb[(wcol + l16) * 512 + sua * 8];
          bf16x8 bb = *(const bf16x8*)&kb[(wcol + l16) * 512 + sub * 8];
          Sa = __builtin_amdgcn_mfma_f32_16x16x32_bf16(qa[ka], ba, Sa, 0, 0, 0);
          Sb = __builtin_amdgcn_mfma_f32_16x16x32_bf16(qa[kbn], bb, Sb, 0, 0, 0);
        }
#pragma unroll
        for (int r = 0; r < 4; r++) sv[s][r] = Sa[r] + Sb[r];
        __syncthreads();
      }
    }
    if (j0 + 4 < jhi) stage(j0 + 4);   // next round's first tile flies under softmax

    // ---- softmax phase (once per 128 tokens) ----
#pragma unroll
    for (int s = 0; s < 4; s++) {
      if (s < ns) {
        int j = j0 + s;
#pragma unroll
        for (int r = 0; r < 4; r++) {
          float x = sv[s][r] * scale;
          if (j == qi) {
            int col = j * 32 + wcol + l16;
            int row = q0 + wrow + 4 * g + r;
            if (col > row) x = -1e10f;
          }
          sv[s][r] = x;
        }
      }
    }
#pragma unroll
    for (int r = 0; r < 4; r++) {
      float v = fmaxf(fmaxf(sv[0][r], sv[1][r]), fmaxf(sv[2][r], sv[3][r]));
#pragma unroll
      for (int off = 1; off < 16; off <<= 1) v = fmaxf(v, __shfl_xor(v, off));
      if (l16 == 0) redm[w & 1][wrow + 4 * g + r] = v;
    }
    __syncthreads();
    float sc2[2][4];
#pragma unroll
    for (int tt = 0; tt < 2; tt++)
#pragma unroll
      for (int r = 0; r < 4; r++) {
        int row = 16 * tt + 4 * g + r;
        float mx = fmaxf(redm[0][row], redm[1][row]);
        float mnew = fmaxf(m_st[tt][r], mx);
        sc2[tt][r] = __expf(m_st[tt][r] - mnew);
        m_st[tt][r] = mnew;
      }
#pragma unroll
    for (int r = 0; r < 4; r++) {
      float psum = 0.f;
#pragma unroll
      for (int s = 0; s < 4; s++) {
        float p = __expf(sv[s][r] - m_st[town][r]);
        Ps[(wrow + 4 * g + r) * 136 + s * 32 + wcol + l16] = f2bf(p);
        psum += p;
      }
      float v = psum;
#pragma unroll
      for (int off = 1; off < 16; off <<= 1) v += __shfl_xor(v, off);
      if (l16 == 0) reds[w & 1][wrow + 4 * g + r] = v;
    }
#pragma unroll
    for (int tt = 0; tt < 2; tt++) {
#pragma unroll
      for (int c2 = 0; c2 < 8; c2++)
#pragma unroll
        for (int r = 0; r < 4; r++) acc[tt][c2][r] *= sc2[tt][r];
#pragma unroll
      for (int r = 0; r < 4; r++) l_st[tt][r] *= sc2[tt][r];
    }
    __syncthreads();
#pragma unroll
    for (int tt = 0; tt < 2; tt++)
#pragma unroll
      for (int r = 0; r < 4; r++) {
        int row = 16 * tt + 4 * g + r;
        l_st[tt][r] += reds[0][row] + reds[1][row];
      }

    // ---- PV phase: P(32x128) @ V(128 x 128-slice), V straight from global ----
    bf16x8 pa0[4], pa1[4];
#pragma unroll
    for (int s = 0; s < 4; s++) {
      pa0[s] = *(const bf16x8*)&Ps[(l16) * 136 + s * 32 + g * 8];
      pa1[s] = *(const bf16x8*)&Ps[(16 + l16) * 136 + s * 32 + g * 8];
    }
#pragma unroll
    for (int c2 = 0; c2 < 8; c2++) {
      int vrow = 128 * w + 16 * c2 + l16;
      bf16x8 vb[4];
#pragma unroll
      for (int s = 0; s < 4; s++)
        if (s < ns) vb[s] = *(const bf16x8*)&vt[(size_t)vrow * 8192 + (size_t)(j0 + s) * 32 + g * 8];
#pragma unroll
      for (int s = 0; s < 4; s++)
        if (s < ns) {
          acc[0][c2] = __builtin_amdgcn_mfma_f32_16x16x32_bf16(pa0[s], vb[s], acc[0][c2], 0, 0, 0);
          acc[1][c2] = __builtin_amdgcn_mfma_f32_16x16x32_bf16(pa1[s], vb[s], acc[1][c2], 0, 0, 0);
        }
    }
  }

  // epilogue: unnormalized partials
#pragma unroll
  for (int tt = 0; tt < 2; tt++)
#pragma unroll
    for (int c2 = 0; c2 < 8; c2++)
#pragma unroll
      for (int r = 0; r < 4; r++) {
        int rowl = 16 * tt + 4 * g + r;
        int col = 128 * w + 16 * c2 + l16;
        Op[(size_t)slot * 16384 + rowl * 512 + col] = f2bf(acc[tt][c2][r]);
      }
  if (w == 0 && l16 == 0) {
#pragma unroll
    for (int tt = 0; tt < 2; tt++)
#pragma unroll
      for (int r = 0; r < 4; r++) {
        int rowl = 16 * tt + 4 * g + r;
        mp[slot * 32 + rowl] = m_st[tt][r];
        lp[slot * 32 + rowl] = l_st[tt][r];
      }
  }
}

// ---------------- combine partials -> normalized O (bf16) ----------------
__global__ __launch_bounds__(256) void k_comb(const u16* __restrict__ Op, const float* __restrict__ mp,
                                              const float* __restrict__ lp, u16* __restrict__ Ob, int CT) {
  const int qi = blockIdx.x;
  const int k0 = qi / CT;
  const int nch = k0 + 1;
  const int base = qi + CT * k0 * (k0 - 1) / 2 + (qi % CT) * k0;
  const int t = threadIdx.x;
  const int row = t >> 3, cg = t & 7;
  float M = -1.0e30f;
#pragma unroll 4
  for (int c = 0; c < 4; c++)
    if (c < nch) M = fmaxf(M, mp[(base + c) * 32 + row]);
  float wgt[4] = {0.f, 0.f, 0.f, 0.f};
  float L = 0.f;
#pragma unroll 4
  for (int c = 0; c < 4; c++)
    if (c < nch) {
      float wv = __expf(mp[(base + c) * 32 + row] - M);
      wgt[c] = wv;
      L += lp[(base + c) * 32 + row] * wv;
    }
  float inv = 1.0f / L;
#pragma unroll
  for (int gsub = 0; gsub < 8; gsub++) {
    int d0 = cg * 64 + gsub * 8;
    float o[8] = {};
#pragma unroll 4
    for (int c = 0; c < 4; c++)
      if (c < nch) {
        bf16x8 v = *(const bf16x8*)&Op[(size_t)(base + c) * 16384 + row * 512 + d0];
#pragma unroll
        for (int e = 0; e < 8; e++) o[e] += wgt[c] * bf2f(v[e]);
      }
    union { u16 h[8]; uint4 u; } pk;
#pragma unroll
    for (int e = 0; e < 8; e++) pk.h[e] = f2bf(o[e] * inv);
    *(uint4*)&Ob[(size_t)(qi * 32 + row) * 512 + d0] = pk.u;
  }
}

extern "C" void kernel_launch(void* const* d_in, const int* in_sizes, int n_in,
                              void* d_out, int out_size, void* d_ws, size_t ws_size,
                              hipStream_t stream) {
  const float* x     = (const float*)d_in[0];
  const float* w_qkv = (const float*)d_in[1];
  const float* b_qkv = (const float*)d_in[2];
  const float* w_out = (const float*)d_in[3];
  const float* b_out = (const float*)d_in[4];
  float* out = (float*)d_out;
  char* ws = (char*)d_ws;
  // base layout (60 MB)
  u16* xb    = (u16*)(ws);               // [8192][1024] bf16   (dead after gemm1)
  u16* wqkvT = (u16*)(ws + 16777216);    // [1536][1024] bf16   (dead after gemm1)
  u16* woutT = (u16*)(ws + 19922944);    // [1024][512]  bf16
  u16* qkv   = (u16*)(ws + 20971520);    // [8192][1536] bf16
  u16* vt    = (u16*)(ws + 46137344);    // [512][8192]  bf16
  u16* Ob    = (u16*)(ws + 54525952);    // [8192][512]  bf16   (ends 62914560)

  int CT, maxc;
  u16* Opart; float* mpart; float* lpart;
  if (ws_size >= (size_t)84049920) {
    CT = 64; maxc = 4;
    Opart = (u16*)(ws + 62914560);       // 640*32*512*2 = 20971520
    mpart = (float*)(ws + 83886080);     // 640*32*4 = 81920
    lpart = (float*)(ws + 83886080 + 81920);
  } else {
    CT = 128; maxc = 2;
    Opart = (u16*)(ws);                  // 384*32*512*2 = 12582912  (xb dead by then)
    mpart = (float*)(ws + 12582912);
    lpart = (float*)(ws + 12582912 + 49152);
  }

  k_cvt<<<4096, 256, 0, stream>>>(x, xb, 8192 * 1024);
  k_tcvt<<<dim3(24, 16), 256, 0, stream>>>(w_qkv, wqkvT, 1024, 1536);
  k_tcvt<<<dim3(16, 8), 256, 0, stream>>>(w_out, woutT, 512, 1024);
  k_gemm<<<dim3(12, 64), 256, 0, stream>>>(xb, wqkvT, b_qkv, qkv, nullptr, 8192, 1536, 1024);
  k_tv<<<dim3(8, 128), 256, 0, stream>>>(qkv, vt);
  k_flash3<<<dim3(maxc, 256), 256, 0, stream>>>(qkv, vt, Opart, mpart, lpart, CT);
  k_comb<<<256, 256, 0, stream>>>(Opart, mpart, lpart, Ob, CT);
  k_gemm<<<dim3(8, 64), 256, 0, stream>>>(Ob, woutT, b_out, nullptr, out, 8192, 1024, 512);
}

// Round 4
// 418.534 us; speedup vs baseline: 2.2424x; 2.1724x over previous
//
#include <hip/hip_runtime.h>

typedef unsigned short u16;
typedef unsigned int u32;
typedef __attribute__((ext_vector_type(8))) short bf16x8;
typedef __attribute__((ext_vector_type(4))) float f32x4;

__device__ __forceinline__ u16 f2bf(float f) {
  u32 u = __float_as_uint(f);
  u += 0x7fffu + ((u >> 16) & 1u);
  return (u16)(u >> 16);
}
__device__ __forceinline__ float bf2f(short h) {
  return __uint_as_float(((u32)(u16)h) << 16);
}

// ---------------- convert x: f32 -> bf16 (straight) ----------------
__global__ __launch_bounds__(256) void k_cvt(const float* __restrict__ in, u16* __restrict__ out, int n) {
  int idx = (blockIdx.x * 256 + threadIdx.x) * 8;
  if (idx >= n) return;
  float4 a = *(const float4*)&in[idx];
  float4 b = *(const float4*)&in[idx + 4];
  union { u16 h[8]; uint4 v; } t;
  t.h[0] = f2bf(a.x); t.h[1] = f2bf(a.y); t.h[2] = f2bf(a.z); t.h[3] = f2bf(a.w);
  t.h[4] = f2bf(b.x); t.h[5] = f2bf(b.y); t.h[6] = f2bf(b.z); t.h[7] = f2bf(b.w);
  *(uint4*)&out[idx] = t.v;
}

// ---------------- transpose+convert: out[c][r] = bf16(in[r][c]); R,C multiples of 64 ----------------
__global__ __launch_bounds__(256) void k_tcvt(const float* __restrict__ in, u16* __restrict__ out, int R, int C) {
  __shared__ u16 T[64 * 72];
  int t = threadIdx.x;
  int r0 = blockIdx.y * 64, c0 = blockIdx.x * 64;
  for (int i = 0; i < 4; i++) {
    int cc = i * 256 + t; int r = cc >> 4; int s = cc & 15;
    float4 v = *(const float4*)&in[(size_t)(r0 + r) * C + c0 + s * 4];
    T[r * 72 + s * 4 + 0] = f2bf(v.x);
    T[r * 72 + s * 4 + 1] = f2bf(v.y);
    T[r * 72 + s * 4 + 2] = f2bf(v.z);
    T[r * 72 + s * 4 + 3] = f2bf(v.w);
  }
  __syncthreads();
  for (int i = 0; i < 2; i++) {
    int cc = i * 256 + t; int c = cc >> 3; int s2 = cc & 7;
    union { u16 h[8]; uint4 v; } tmp;
    for (int e = 0; e < 8; e++) tmp.h[e] = T[(s2 * 8 + e) * 72 + c];
    *(uint4*)&out[(size_t)(c0 + c) * R + r0 + s2 * 8] = tmp.v;
  }
}

// ---------------- transpose v-part of qkv (bf16) into Vt[512][8192] ----------------
__global__ __launch_bounds__(256) void k_tv(const u16* __restrict__ qkv, u16* __restrict__ vt) {
  __shared__ u16 T[64 * 72];
  int t = threadIdx.x;
  int r0 = blockIdx.y * 64;   // token rows
  int d0 = blockIdx.x * 64;   // head-dim rows of vt
  for (int i = 0; i < 2; i++) {
    int cc = i * 256 + t; int r = cc >> 3; int s = cc & 7;
    *(uint4*)&T[r * 72 + s * 8] = *(const uint4*)&qkv[(size_t)(r0 + r) * 1536 + 1024 + d0 + s * 8];
  }
  __syncthreads();
  for (int i = 0; i < 2; i++) {
    int cc = i * 256 + t; int d = cc >> 3; int s2 = cc & 7;
    union { u16 h[8]; uint4 v; } tmp;
    for (int e = 0; e < 8; e++) tmp.h[e] = T[(s2 * 8 + e) * 72 + d];
    *(uint4*)&vt[(size_t)(d0 + d) * 8192 + r0 + s2 * 8] = tmp.v;
  }
}

// ---------------- GEMM: C[M,N] = A[M,K] @ Bt[N,K]^T + bias; bf16 in, bf16 or f32 out ----------------
__global__ __launch_bounds__(256) void k_gemm(const u16* __restrict__ A, const u16* __restrict__ Bt,
                                              const float* __restrict__ bias,
                                              u16* __restrict__ Cb, float* __restrict__ Cf,
                                              int M, int N, int K) {
  __shared__ u16 As[128 * 64];
  __shared__ u16 Bs[128 * 64];
  const int t = threadIdx.x;
  const int l = t & 63, w = t >> 6;
  const int l16 = l & 15, g = l >> 4;
  const int m0 = blockIdx.y * 128, n0 = blockIdx.x * 128;
  const int wr = (w >> 1) * 64, wc = (w & 1) * 64;
  f32x4 acc[4][4] = {};
  for (int kk = 0; kk < K; kk += 64) {
    __syncthreads();
#pragma unroll
    for (int i = 0; i < 4; i++) {
      int c = i * 256 + t;
      int r = c >> 3, g2 = c & 7;
      int sg = g2 ^ (r & 7);
      __builtin_amdgcn_global_load_lds(
          (const __attribute__((address_space(1))) u32*)(A + (size_t)(m0 + r) * K + kk + sg * 8),
          (__attribute__((address_space(3))) u32*)&As[c * 8], 16, 0, 0);
      __builtin_amdgcn_global_load_lds(
          (const __attribute__((address_space(1))) u32*)(Bt + (size_t)(n0 + r) * K + kk + sg * 8),
          (__attribute__((address_space(3))) u32*)&Bs[c * 8], 16, 0, 0);
    }
    __syncthreads();
#pragma unroll
    for (int kh = 0; kh < 2; kh++) {
      bf16x8 a[4];
#pragma unroll
      for (int mi = 0; mi < 4; mi++) {
        int row = wr + 16 * mi + l16;
        int s = (kh * 4 + g) ^ (row & 7);
        a[mi] = *(const bf16x8*)&As[row * 64 + s * 8];
      }
#pragma unroll
      for (int ni = 0; ni < 4; ni++) {
        int row = wc + 16 * ni + l16;
        int s = (kh * 4 + g) ^ (row & 7);
        bf16x8 b = *(const bf16x8*)&Bs[row * 64 + s * 8];
#pragma unroll
        for (int mi = 0; mi < 4; mi++)
          acc[mi][ni] = __builtin_amdgcn_mfma_f32_16x16x32_bf16(a[mi], b, acc[mi][ni], 0, 0, 0);
      }
    }
  }
#pragma unroll
  for (int ni = 0; ni < 4; ni++) {
    int col = n0 + wc + 16 * ni + l16;
    float bv = bias[col];
#pragma unroll
    for (int mi = 0; mi < 4; mi++) {
      int row0 = m0 + wr + 16 * mi + 4 * g;
#pragma unroll
      for (int r = 0; r < 4; r++) {
        float v = acc[mi][ni][r] + bv;
        if (Cf) Cf[(size_t)(row0 + r) * N + col] = v;
        else    Cb[(size_t)(row0 + r) * N + col] = f2bf(v);
      }
    }
  }
}

// ---------------- flash attention v4: BQ=128, 8 waves, KV tile 64 staged in LDS ----------------
// Wave w owns Q rows [q0+16w, q0+16w+16). Block (c, qb): KV 64-token tiles [c*CT, min((c+1)*CT, 2qb+2)).
// Writes UNNORMALIZED O[128][512] bf16 + per-row (m,l) into slot.
// H = CT/2; nch(qb) = ceil((qb+1)/H); base(qb) = (a+1)*((H/2)*a + b), a=qb/H, b=qb%H; slot = base+c.
__global__ __launch_bounds__(512, 2) void k_flash4(const u16* __restrict__ qkv, const u16* __restrict__ vt,
                                                   u16* __restrict__ Op, float* __restrict__ ml, int CT) {
  __shared__ u16 Ks[64 * 512];    // 64 KB, [kv][d], 16B units XOR-swizzled by kv-row
  __shared__ u16 Vs[512 * 64];    // 64 KB, [d][kv], 16B units XOR-swizzled by d-row
  __shared__ u16 Ps[8][16 * 72];  // 18 KB, per-wave P strip [16 q][64 kv], padded stride
  const int qb = blockIdx.y, c = blockIdx.x;
  const int H = CT >> 1;
  const int nch = (qb + H) / H;               // ceil((qb+1)/H)
  if (c >= nch) return;
  const int a = qb / H, b = qb % H;
  const int slot = (a + 1) * ((H >> 1) * a + b) + c;
  const int tlo = c * CT;
  const int thi = min((c + 1) * CT, 2 * qb + 2);
  const int t = threadIdx.x;
  const int l = t & 63, w = t >> 6;
  const int l16 = l & 15, g = l >> 4;
  const int q0 = qb * 128;
  const int qpos = q0 + 16 * w + 4 * g;       // +r for exact row
  const float scale = 0.044194173824159216f;  // 1/sqrt(512)

  // hoist Q A-fragments: row = q0+16w+l16, k = 32ks+8g..+7  (64 VGPRs)
  bf16x8 qa[16];
#pragma unroll
  for (int ks = 0; ks < 16; ks++)
    qa[ks] = *(const bf16x8*)&qkv[(size_t)(q0 + 16 * w + l16) * 1536 + ks * 32 + g * 8];

  f32x4 acc[32] = {};                          // O: d = 16db+l16, row = 16w+4g+r
  float m_st[4], l_st[4];
#pragma unroll
  for (int r = 0; r < 4; r++) { m_st[r] = -1.0e30f; l_st[r] = 0.f; }

  for (int jt = tlo; jt < thi; ++jt) {
    const int tok0 = jt * 64;
    __syncthreads();                           // all waves done reading Ks/Vs of prev tile
    // ---- stage K (64x512) and V (512x64) via global_load_lds, swizzled source ----
#pragma unroll
    for (int i = 0; i < 8; i++) {
      int cc = i * 512 + t;                    // K 16B unit 0..4095: row=cc>>6, u=cc&63
      int r = cc >> 6, u = cc & 63;
      int su = (u & 56) | ((u & 7) ^ (r & 7));
      __builtin_amdgcn_global_load_lds(
          (const __attribute__((address_space(1))) u32*)(qkv + (size_t)(tok0 + r) * 1536 + 512 + su * 8),
          (__attribute__((address_space(3))) u32*)&Ks[cc * 8], 16, 0, 0);
    }
#pragma unroll
    for (int i = 0; i < 8; i++) {
      int cc = i * 512 + t;                    // V 16B unit 0..4095: d=cc>>3, u=cc&7
      int d = cc >> 3, u = cc & 7;
      int su = u ^ (d & 7);
      __builtin_amdgcn_global_load_lds(
          (const __attribute__((address_space(1))) u32*)(vt + (size_t)d * 8192 + tok0 + su * 8),
          (__attribute__((address_space(3))) u32*)&Vs[cc * 8], 16, 0, 0);
    }
    __syncthreads();                           // staged (vmcnt drained at barrier)

    // ---- QK^T: per wave 16 rows x 64 cols, K-dim 512; 4 independent chains ----
    f32x4 S[4];
#pragma unroll
    for (int cb = 0; cb < 4; cb++) S[cb] = (f32x4){0.f, 0.f, 0.f, 0.f};
#pragma unroll
    for (int ks = 0; ks < 16; ks++) {
      int u = 4 * ks + g;
      int su = (u & 56) | ((u & 7) ^ (l16 & 7));
#pragma unroll
      for (int cb = 0; cb < 4; cb++) {
        bf16x8 kb = *(const bf16x8*)&Ks[(16 * cb + l16) * 512 + su * 8];
        S[cb] = __builtin_amdgcn_mfma_f32_16x16x32_bf16(qa[ks], kb, S[cb], 0, 0, 0);
      }
    }
    // ---- mask + scale ----
#pragma unroll
    for (int cb = 0; cb < 4; cb++) {
      int kvpos = tok0 + 16 * cb + l16;
#pragma unroll
      for (int r = 0; r < 4; r++) {
        float x = S[cb][r] * scale;
        if (kvpos > qpos + r) x = -1e10f;
        S[cb][r] = x;
      }
    }
    // ---- wave-local softmax (no barriers) ----
    float sc_old[4];
#pragma unroll
    for (int r = 0; r < 4; r++) {
      float v = fmaxf(fmaxf(S[0][r], S[1][r]), fmaxf(S[2][r], S[3][r]));
#pragma unroll
      for (int off = 1; off < 16; off <<= 1) v = fmaxf(v, __shfl_xor(v, off));
      float mnew = fmaxf(m_st[r], v);
      sc_old[r] = __expf(m_st[r] - mnew);
      m_st[r] = mnew;
    }
#pragma unroll
    for (int r = 0; r < 4; r++) {
      float psum = 0.f;
#pragma unroll
      for (int cb = 0; cb < 4; cb++) {
        float p = __expf(S[cb][r] - m_st[r]);
        Ps[w][(4 * g + r) * 72 + 16 * cb + l16] = f2bf(p);
        psum += p;
      }
#pragma unroll
      for (int off = 1; off < 16; off <<= 1) psum += __shfl_xor(psum, off);
      l_st[r] = l_st[r] * sc_old[r] + psum;
    }
#pragma unroll
    for (int db = 0; db < 32; db++)
#pragma unroll
      for (int r = 0; r < 4; r++) acc[db][r] *= sc_old[r];

    // ---- PV: O[16x512] += P[16x64] @ V[64x512]; P from own LDS strip, V from shared LDS ----
    bf16x8 pa0 = *(const bf16x8*)&Ps[w][l16 * 72 + 0 * 32 + g * 8];
    bf16x8 pa1 = *(const bf16x8*)&Ps[w][l16 * 72 + 1 * 32 + g * 8];
#pragma unroll
    for (int db = 0; db < 32; db++) {
      int d = 16 * db + l16;
      int u0 = (4 * 0 + g) ^ (l16 & 7);
      int u1 = (4 * 1 + g) ^ (l16 & 7);
      bf16x8 vb0 = *(const bf16x8*)&Vs[d * 64 + u0 * 8];
      bf16x8 vb1 = *(const bf16x8*)&Vs[d * 64 + u1 * 8];
      acc[db] = __builtin_amdgcn_mfma_f32_16x16x32_bf16(pa0, vb0, acc[db], 0, 0, 0);
      acc[db] = __builtin_amdgcn_mfma_f32_16x16x32_bf16(pa1, vb1, acc[db], 0, 0, 0);
    }
  }

  // ---- epilogue: unnormalized O partial + (m,l) ----
#pragma unroll
  for (int db = 0; db < 32; db++)
#pragma unroll
    for (int r = 0; r < 4; r++) {
      int rowl = 16 * w + 4 * g + r;
      Op[(size_t)slot * 65536 + rowl * 512 + 16 * db + l16] = f2bf(acc[db][r]);
    }
  if (l16 == 0) {
#pragma unroll
    for (int r = 0; r < 4; r++) {
      int rowl = 16 * w + 4 * g + r;
      ml[slot * 256 + rowl * 2 + 0] = m_st[r];
      ml[slot * 256 + rowl * 2 + 1] = l_st[r];
    }
  }
}

// ---------------- combine partials -> normalized O (bf16) ----------------
__global__ __launch_bounds__(512) void k_comb2(const u16* __restrict__ Op, const float* __restrict__ ml,
                                               u16* __restrict__ Ob, int CT) {
  const int qb = blockIdx.x;
  const int H = CT >> 1;
  const int nch = (qb + H) / H;
  const int a = qb / H, b = qb % H;
  const int base = (a + 1) * ((H >> 1) * a + b);
  const int t = threadIdx.x;
  const int row = t >> 2, q = t & 3;
  float M = -3.0e38f;
  float mv[4], lv[4];
#pragma unroll 4
  for (int c = 0; c < 4; c++)
    if (c < nch) {
      mv[c] = ml[(base + c) * 256 + row * 2 + 0];
      lv[c] = ml[(base + c) * 256 + row * 2 + 1];
      M = fmaxf(M, mv[c]);
    }
  float L = 0.f, wgt[4] = {0.f, 0.f, 0.f, 0.f};
#pragma unroll 4
  for (int c = 0; c < 4; c++)
    if (c < nch) {
      wgt[c] = __expf(mv[c] - M);
      L += wgt[c] * lv[c];
    }
  float inv = 1.0f / L;
#pragma unroll
  for (int e = 0; e < 16; e++) {
    int d0 = q * 128 + e * 8;
    float o[8] = {};
#pragma unroll 4
    for (int c = 0; c < 4; c++)
      if (c < nch) {
        bf16x8 v = *(const bf16x8*)&Op[(size_t)(base + c) * 65536 + row * 512 + d0];
#pragma unroll
        for (int j = 0; j < 8; j++) o[j] += wgt[c] * bf2f(v[j]);
      }
    union { u16 h[8]; uint4 u; } pk;
#pragma unroll
    for (int j = 0; j < 8; j++) pk.h[j] = f2bf(o[j] * inv);
    *(uint4*)&Ob[(size_t)(qb * 128 + row) * 512 + d0] = pk.u;
  }
}

extern "C" void kernel_launch(void* const* d_in, const int* in_sizes, int n_in,
                              void* d_out, int out_size, void* d_ws, size_t ws_size,
                              hipStream_t stream) {
  const float* x     = (const float*)d_in[0];
  const float* w_qkv = (const float*)d_in[1];
  const float* b_qkv = (const float*)d_in[2];
  const float* w_out = (const float*)d_in[3];
  const float* b_out = (const float*)d_in[4];
  float* out = (float*)d_out;
  char* ws = (char*)d_ws;
  // base layout (60 MB)
  u16* xb    = (u16*)(ws);               // [8192][1024] bf16   (dead after gemm1)
  u16* wqkvT = (u16*)(ws + 16777216);    // [1536][1024] bf16   (dead after gemm1)
  u16* woutT = (u16*)(ws + 19922944);    // [1024][512]  bf16
  u16* qkv   = (u16*)(ws + 20971520);    // [8192][1536] bf16
  u16* vt    = (u16*)(ws + 46137344);    // [512][8192]  bf16
  u16* Ob    = (u16*)(ws + 54525952);    // [8192][512]  bf16   (ends 62914560)

  // flash4 partials: CT in 64-token tiles. Primary: CT=32 (2048-tok chunks), 160 slots.
  // Fallback (small ws): CT=64 (4096-tok chunks), 96 slots overlaid on dead xb region.
  int CT, maxc;
  u16* Opart; float* mlp;
  if (ws_size >= (size_t)84049920) {
    CT = 32; maxc = 4;
    Opart = (u16*)(ws + 62914560);       // 160*65536*2 = 20971520 -> ends 83886080
    mlp   = (float*)(ws + 83886080);     // 160*256*4 = 163840 -> ends 84049920
  } else {
    CT = 64; maxc = 2;
    Opart = (u16*)(ws);                  // 96*65536*2 = 12582912 (xb dead by then)
    mlp   = (float*)(ws + 12582912);     // 96*256*4 = 98304
  }

  k_cvt<<<4096, 256, 0, stream>>>(x, xb, 8192 * 1024);
  k_tcvt<<<dim3(24, 16), 256, 0, stream>>>(w_qkv, wqkvT, 1024, 1536);
  k_tcvt<<<dim3(16, 8), 256, 0, stream>>>(w_out, woutT, 512, 1024);
  k_gemm<<<dim3(12, 64), 256, 0, stream>>>(xb, wqkvT, b_qkv, qkv, nullptr, 8192, 1536, 1024);
  k_tv<<<dim3(8, 128), 256, 0, stream>>>(qkv, vt);
  k_flash4<<<dim3(maxc, 64), 512, 0, stream>>>(qkv, vt, Opart, mlp, CT);
  k_comb2<<<64, 512, 0, stream>>>(Opart, mlp, Ob, CT);
  k_gemm<<<dim3(8, 64), 256, 0, stream>>>(Ob, woutT, b_out, nullptr, out, 8192, 1024, 512);
}

// Round 5
// 383.684 us; speedup vs baseline: 2.4461x; 1.0908x over previous
//
#include <hip/hip_runtime.h>

typedef unsigned short u16;
typedef unsigned int u32;
typedef __attribute__((ext_vector_type(8))) short bf16x8;
typedef __attribute__((ext_vector_type(4))) float f32x4;

__device__ __forceinline__ u16 f2bf(float f) {
  u32 u = __float_as_uint(f);
  u += 0x7fffu + ((u >> 16) & 1u);
  return (u16)(u >> 16);
}
__device__ __forceinline__ float bf2f(short h) {
  return __uint_as_float(((u32)(u16)h) << 16);
}

// ---------------- convert x: f32 -> bf16 (straight) ----------------
__global__ __launch_bounds__(256) void k_cvt(const float* __restrict__ in, u16* __restrict__ out, int n) {
  int idx = (blockIdx.x * 256 + threadIdx.x) * 8;
  if (idx >= n) return;
  float4 a = *(const float4*)&in[idx];
  float4 b = *(const float4*)&in[idx + 4];
  union { u16 h[8]; uint4 v; } t;
  t.h[0] = f2bf(a.x); t.h[1] = f2bf(a.y); t.h[2] = f2bf(a.z); t.h[3] = f2bf(a.w);
  t.h[4] = f2bf(b.x); t.h[5] = f2bf(b.y); t.h[6] = f2bf(b.z); t.h[7] = f2bf(b.w);
  *(uint4*)&out[idx] = t.v;
}

// ---------------- transpose+convert: out[c][r] = bf16(in[r][c]) ----------------
__global__ __launch_bounds__(256) void k_tcvt(const float* __restrict__ in, u16* __restrict__ out, int R, int C) {
  __shared__ u16 T[64 * 72];
  int t = threadIdx.x;
  int r0 = blockIdx.y * 64, c0 = blockIdx.x * 64;
  for (int i = 0; i < 4; i++) {
    int cc = i * 256 + t; int r = cc >> 4; int s = cc & 15;
    float4 v = *(const float4*)&in[(size_t)(r0 + r) * C + c0 + s * 4];
    T[r * 72 + s * 4 + 0] = f2bf(v.x);
    T[r * 72 + s * 4 + 1] = f2bf(v.y);
    T[r * 72 + s * 4 + 2] = f2bf(v.z);
    T[r * 72 + s * 4 + 3] = f2bf(v.w);
  }
  __syncthreads();
  for (int i = 0; i < 2; i++) {
    int cc = i * 256 + t; int c = cc >> 3; int s2 = cc & 7;
    union { u16 h[8]; uint4 v; } tmp;
    for (int e = 0; e < 8; e++) tmp.h[e] = T[(s2 * 8 + e) * 72 + c];
    *(uint4*)&out[(size_t)(c0 + c) * R + r0 + s2 * 8] = tmp.v;
  }
}

// ---------------- transpose v-part of qkv into Vt[512][8192] ----------------
__global__ __launch_bounds__(256) void k_tv(const u16* __restrict__ qkv, u16* __restrict__ vt) {
  __shared__ u16 T[64 * 72];
  int t = threadIdx.x;
  int r0 = blockIdx.y * 64, d0 = blockIdx.x * 64;
  for (int i = 0; i < 2; i++) {
    int cc = i * 256 + t; int r = cc >> 3; int s = cc & 7;
    *(uint4*)&T[r * 72 + s * 8] = *(const uint4*)&qkv[(size_t)(r0 + r) * 1536 + 1024 + d0 + s * 8];
  }
  __syncthreads();
  for (int i = 0; i < 2; i++) {
    int cc = i * 256 + t; int d = cc >> 3; int s2 = cc & 7;
    union { u16 h[8]; uint4 v; } tmp;
    for (int e = 0; e < 8; e++) tmp.h[e] = T[(s2 * 8 + e) * 72 + d];
    *(uint4*)&vt[(size_t)(d0 + d) * 8192 + r0 + s2 * 8] = tmp.v;
  }
}

// ---------------- GEMM (m97 structure) ----------------
__global__ __launch_bounds__(256) void k_gemm(const u16* __restrict__ A, const u16* __restrict__ Bt,
                                              const float* __restrict__ bias,
                                              u16* __restrict__ Cb, float* __restrict__ Cf,
                                              int M, int N, int K) {
  __shared__ u16 As[128 * 64];
  __shared__ u16 Bs[128 * 64];
  const int t = threadIdx.x;
  const int l = t & 63, w = t >> 6;
  const int l16 = l & 15, g = l >> 4;
  const int m0 = blockIdx.y * 128, n0 = blockIdx.x * 128;
  const int wr = (w >> 1) * 64, wc = (w & 1) * 64;
  f32x4 acc[4][4] = {};
  for (int kk = 0; kk < K; kk += 64) {
    __syncthreads();
#pragma unroll
    for (int i = 0; i < 4; i++) {
      int c = i * 256 + t;
      int r = c >> 3, g2 = c & 7;
      int sg = g2 ^ (r & 7);
      __builtin_amdgcn_global_load_lds(
          (const __attribute__((address_space(1))) u32*)(A + (size_t)(m0 + r) * K + kk + sg * 8),
          (__attribute__((address_space(3))) u32*)&As[c * 8], 16, 0, 0);
      __builtin_amdgcn_global_load_lds(
          (const __attribute__((address_space(1))) u32*)(Bt + (size_t)(n0 + r) * K + kk + sg * 8),
          (__attribute__((address_space(3))) u32*)&Bs[c * 8], 16, 0, 0);
    }
    __syncthreads();
#pragma unroll
    for (int kh = 0; kh < 2; kh++) {
      bf16x8 a[4];
#pragma unroll
      for (int mi = 0; mi < 4; mi++) {
        int row = wr + 16 * mi + l16;
        int s = (kh * 4 + g) ^ (row & 7);
        a[mi] = *(const bf16x8*)&As[row * 64 + s * 8];
      }
#pragma unroll
      for (int ni = 0; ni < 4; ni++) {
        int row = wc + 16 * ni + l16;
        int s = (kh * 4 + g) ^ (row & 7);
        bf16x8 b = *(const bf16x8*)&Bs[row * 64 + s * 8];
#pragma unroll
        for (int mi = 0; mi < 4; mi++)
          acc[mi][ni] = __builtin_amdgcn_mfma_f32_16x16x32_bf16(a[mi], b, acc[mi][ni], 0, 0, 0);
      }
    }
  }
#pragma unroll
  for (int ni = 0; ni < 4; ni++) {
    int col = n0 + wc + 16 * ni + l16;
    float bv = bias[col];
#pragma unroll
    for (int mi = 0; mi < 4; mi++) {
      int row0 = m0 + wr + 16 * mi + 4 * g;
#pragma unroll
      for (int r = 0; r < 4; r++) {
        float v = acc[mi][ni][r] + bv;
        if (Cf) Cf[(size_t)(row0 + r) * N + col] = v;
        else    Cb[(size_t)(row0 + r) * N + col] = f2bf(v);
      }
    }
  }
}

// ---------------- flash v5: BQ=128, 8 waves, 32-tok KV tiles, double-buffered, 1 barrier/step ----
// Block (c, qb): KV 32-tok tiles [c*CT, min((c+1)*CT, (qb+1)*4)), CT = 4*Gq, Gq = 1<<lgGq.
// nch(qb) = (qb>>lgGq)+1; base(qb) = (a+1)*((Gq/2)*a + b); slot = base + c.
// Op layout (per slot, 65536 u16): [wave][db2(0..15)][lane][8 u16: {db even r0..3, db odd r0..3}]
__global__ __launch_bounds__(512, 2) void k_flash5(const u16* __restrict__ qkv, const u16* __restrict__ vt,
                                                   u16* __restrict__ opA, u16* __restrict__ opB,
                                                   float* __restrict__ ml, int lgGq, int SPLIT) {
  __shared__ u16 Ks[2][32 * 512];   // [kv 32][d 512], 16B units XOR-swizzled by kv-row
  __shared__ u16 Vs[2][512 * 32];   // subtiled: unit U(d,u) = (d>>3)*32 + (d&7) + 8u
  __shared__ u16 Ps[8][16 * 40];    // per-wave P strip [16 q][32 kv], stride 40 u16
  const int qb = blockIdx.y, c = blockIdx.x;
  const int Gq = 1 << lgGq;
  const int a = qb >> lgGq, b = qb & (Gq - 1);
  const int nch = a + 1;
  if (c >= nch) return;
  const int slot = (a + 1) * ((Gq >> 1) * a + b) + c;
  const int CT = Gq << 2;
  const int jlo = c * CT;
  const int jhi = min(jlo + CT, (qb + 1) * 4);
  const int t = threadIdx.x;
  const int l = t & 63, w = t >> 6;
  const int l16 = l & 15, g = l >> 4;
  const int q0 = qb * 128;
  const int qpos = q0 + 16 * w + 4 * g;        // +r for exact row
  const float scale = 0.044194173824159216f;   // 1/sqrt(512)

  auto stageK = [&](int jt, int buf) {
    const u16* src = qkv + (size_t)(jt * 32) * 1536 + 512;
#pragma unroll
    for (int i = 0; i < 4; i++) {
      int cc = i * 512 + t;                    // 16B unit 0..2047
      int r = cc >> 6, u = cc & 63;
      int su = (u & 56) | ((u & 7) ^ (r & 7));
      __builtin_amdgcn_global_load_lds(
          (const __attribute__((address_space(1))) u32*)(src + (size_t)r * 1536 + su * 8),
          (__attribute__((address_space(3))) u32*)&Ks[buf][cc * 8], 16, 0, 0);
    }
  };
  auto stageV = [&](int jt, int buf) {
    const int tok0 = jt * 32;
#pragma unroll
    for (int i = 0; i < 4; i++) {
      int cc = i * 512 + t;                    // unit U = cc: grp = U>>5, r5 = U&31
      int grp = cc >> 5, r5 = cc & 31;
      int d = grp * 8 + (r5 & 7), u = r5 >> 3;
      __builtin_amdgcn_global_load_lds(
          (const __attribute__((address_space(1))) u32*)(vt + (size_t)d * 8192 + tok0 + u * 8),
          (__attribute__((address_space(3))) u32*)&Vs[buf][cc * 8], 16, 0, 0);
    }
  };

  // hoist Q A-fragments: row = q0+16w+l16, k = 32ks + 8g + j (64 VGPRs)
  bf16x8 qa[16];
#pragma unroll
  for (int ks = 0; ks < 16; ks++)
    qa[ks] = *(const bf16x8*)&qkv[(size_t)(q0 + 16 * w + l16) * 1536 + ks * 32 + g * 8];

  f32x4 acc[32] = {};                          // O: col = 16db + l16, row = 16w + 4g + r
  float m_st[4], l_st[4];
#pragma unroll
  for (int r = 0; r < 4; r++) { m_st[r] = -1.0e30f; l_st[r] = 0.f; }

  stageK(jlo, jlo & 1);
  stageV(jlo, jlo & 1);
  __syncthreads();

  const int vbase = ((l16 >> 3) * 32 + (l16 & 7)) * 8 + g * 64;  // u16 offset; +db*512

  for (int jt = jlo; jt < jhi; ++jt) {
    const int buf = jt & 1;
    const int tok0 = jt * 32;
    if (jt + 1 < jhi) { stageK(jt + 1, buf ^ 1); stageV(jt + 1, buf ^ 1); }

    // ---- QK^T: 16 rows x 32 cols per wave, K-dim 512, 2 chains ----
    f32x4 S0 = {0.f, 0.f, 0.f, 0.f}, S1 = {0.f, 0.f, 0.f, 0.f};
#pragma unroll
    for (int ks = 0; ks < 16; ks++) {
      int u = 4 * ks + g;
      int su = (u & 56) | ((u & 7) ^ (l16 & 7));
      bf16x8 k0 = *(const bf16x8*)&Ks[buf][l16 * 512 + su * 8];
      bf16x8 k1 = *(const bf16x8*)&Ks[buf][(16 + l16) * 512 + su * 8];
      S0 = __builtin_amdgcn_mfma_f32_16x16x32_bf16(qa[ks], k0, S0, 0, 0, 0);
      S1 = __builtin_amdgcn_mfma_f32_16x16x32_bf16(qa[ks], k1, S1, 0, 0, 0);
    }
    // ---- scale + causal mask (wave-uniform skip when tile fully visible) ----
#pragma unroll
    for (int r = 0; r < 4; r++) { S0[r] *= scale; S1[r] *= scale; }
    if (tok0 + 31 > q0 + 16 * w) {
      int kv0 = tok0 + l16, kv1 = tok0 + 16 + l16;
#pragma unroll
      for (int r = 0; r < 4; r++) {
        if (kv0 > qpos + r) S0[r] = -1e10f;
        if (kv1 > qpos + r) S1[r] = -1e10f;
      }
    }
    // ---- wave-local online softmax with defer-max (THR=6) ----
    float pm[4];
#pragma unroll
    for (int r = 0; r < 4; r++) {
      float v = fmaxf(S0[r], S1[r]);
#pragma unroll
      for (int off = 1; off < 16; off <<= 1) v = fmaxf(v, __shfl_xor(v, off));
      pm[r] = v;
    }
    float sc[4] = {1.f, 1.f, 1.f, 1.f};
    int need = (pm[0] > m_st[0] + 6.f) | (pm[1] > m_st[1] + 6.f) |
               (pm[2] > m_st[2] + 6.f) | (pm[3] > m_st[3] + 6.f);
    if (__any(need)) {
#pragma unroll
      for (int r = 0; r < 4; r++) {
        float mn = fmaxf(m_st[r], pm[r]);
        sc[r] = __expf(m_st[r] - mn);
        m_st[r] = mn;
      }
#pragma unroll
      for (int db = 0; db < 32; db++)
#pragma unroll
        for (int r = 0; r < 4; r++) acc[db][r] *= sc[r];
    }
#pragma unroll
    for (int r = 0; r < 4; r++) {
      float p0 = __expf(S0[r] - m_st[r]);
      float p1 = __expf(S1[r] - m_st[r]);
      Ps[w][(4 * g + r) * 40 + l16] = f2bf(p0);
      Ps[w][(4 * g + r) * 40 + 16 + l16] = f2bf(p1);
      float ps = p0 + p1;
#pragma unroll
      for (int off = 1; off < 16; off <<= 1) ps += __shfl_xor(ps, off);
      l_st[r] = l_st[r] * sc[r] + ps;
    }
    // ---- PV: O[16x512] += P[16x32] @ V[32x512] ----
    bf16x8 pa = *(const bf16x8*)&Ps[w][l16 * 40 + g * 8];
#pragma unroll
    for (int db = 0; db < 32; db++) {
      bf16x8 vb = *(const bf16x8*)&Vs[buf][db * 512 + vbase];
      acc[db] = __builtin_amdgcn_mfma_f32_16x16x32_bf16(pa, vb, acc[db], 0, 0, 0);
    }
    __syncthreads();   // drains vmcnt (prefetch jt+1 done) + protects both buffers
  }

  // ---- epilogue: vectorized unnormalized partials ----
  u16* op = (slot < SPLIT) ? (opA + (size_t)slot * 65536)
                           : (opB + (size_t)(slot - SPLIT) * 65536);
  uint4* opw = (uint4*)op;
#pragma unroll
  for (int db2 = 0; db2 < 16; db2++) {
    union { u16 h[8]; uint4 v; } pk;
#pragma unroll
    for (int j = 0; j < 8; j++) pk.h[j] = f2bf(acc[2 * db2 + (j >> 2)][j & 3]);
    opw[w * 1024 + db2 * 64 + l] = pk.v;
  }
  if (l16 == 0) {
#pragma unroll
    for (int r = 0; r < 4; r++) {
      int rowl = 16 * w + 4 * g + r;
      ml[slot * 256 + rowl * 2 + 0] = m_st[r];
      ml[slot * 256 + rowl * 2 + 1] = l_st[r];
    }
  }
}

// ---------------- combine partials -> normalized O (bf16) ----------------
__global__ __launch_bounds__(512) void k_comb3(const u16* __restrict__ opA, const u16* __restrict__ opB,
                                               const float* __restrict__ ml, u16* __restrict__ Ob,
                                               int lgGq, int SPLIT) {
  const int qb = blockIdx.x;
  const int Gq = 1 << lgGq;
  const int a = qb >> lgGq, b = qb & (Gq - 1);
  const int nch = a + 1;
  const int base = (a + 1) * ((Gq >> 1) * a + b);
  const int t = threadIdx.x;
  const int l = t & 63, w = t >> 6;
  const int l16 = l & 15, g = l >> 4;
  float mv[8][4], lv[8][4], wgt[8][4];
  float M[4] = {-3.0e38f, -3.0e38f, -3.0e38f, -3.0e38f};
#pragma unroll 8
  for (int c = 0; c < 8; c++)
    if (c < nch)
#pragma unroll
      for (int r = 0; r < 4; r++) {
        int rowl = 16 * w + 4 * g + r;
        mv[c][r] = ml[(base + c) * 256 + rowl * 2 + 0];
        lv[c][r] = ml[(base + c) * 256 + rowl * 2 + 1];
        M[r] = fmaxf(M[r], mv[c][r]);
      }
  float L[4] = {0.f, 0.f, 0.f, 0.f};
#pragma unroll 8
  for (int c = 0; c < 8; c++)
    if (c < nch)
#pragma unroll
      for (int r = 0; r < 4; r++) {
        wgt[c][r] = __expf(mv[c][r] - M[r]);
        L[r] += wgt[c][r] * lv[c][r];
      }
  float inv[4];
#pragma unroll
  for (int r = 0; r < 4; r++) inv[r] = 1.0f / L[r];
#pragma unroll
  for (int db2 = 0; db2 < 16; db2++) {
    float o[8] = {};
#pragma unroll 8
    for (int c = 0; c < 8; c++)
      if (c < nch) {
        int slot = base + c;
        const uint4* src = (slot < SPLIT) ? (const uint4*)(opA + (size_t)slot * 65536)
                                          : (const uint4*)(opB + (size_t)(slot - SPLIT) * 65536);
        uint4 v = src[w * 1024 + db2 * 64 + l];
        union { uint4 u; u16 h[8]; } un; un.u = v;
#pragma unroll
        for (int j = 0; j < 8; j++) o[j] += wgt[c][j & 3] * bf2f(un.h[j]);
      }
#pragma unroll
    for (int j = 0; j < 8; j++) {
      int row = qb * 128 + 16 * w + 4 * g + (j & 3);
      int col = 32 * db2 + 16 * (j >> 2) + l16;
      Ob[(size_t)row * 512 + col] = f2bf(o[j] * inv[j & 3]);
    }
  }
}

extern "C" void kernel_launch(void* const* d_in, const int* in_sizes, int n_in,
                              void* d_out, int out_size, void* d_ws, size_t ws_size,
                              hipStream_t stream) {
  const float* x     = (const float*)d_in[0];
  const float* w_qkv = (const float*)d_in[1];
  const float* b_qkv = (const float*)d_in[2];
  const float* w_out = (const float*)d_in[3];
  const float* b_out = (const float*)d_in[4];
  float* out = (float*)d_out;
  char* ws = (char*)d_ws;
  // base layout
  u16* xb    = (u16*)(ws);               // [8192][1024] bf16 (dead after gemm1 -> Op region A)
  u16* wqkvT = (u16*)(ws + 16777216);    // [1536][1024] bf16 (dead after gemm1)
  u16* woutT = (u16*)(ws + 19922944);    // [1024][512]  bf16
  u16* qkv   = (u16*)(ws + 20971520);    // [8192][1536] bf16
  u16* vt    = (u16*)(ws + 46137344);    // [512][8192]  bf16
  u16* Ob    = (u16*)(ws + 54525952);    // [8192][512]  bf16 (ends 62914560)

  // partials: region A = slots [0,152) over dead xb+wqkvT (152*131072 = 19922944 exact);
  //           region B = slots [152, ...) after Ob.
  const int SPLIT = 152;
  u16* opA = (u16*)ws;
  u16* opB = (u16*)(ws + 62914560);
  int lgGq, maxc; size_t mlOff;
  if (ws_size >= (size_t)81035264) { lgGq = 3; maxc = 8; mlOff = 80740352; }  // 288 slots, 1024-tok chunks
  else                             { lgGq = 4; maxc = 4; mlOff = 63963136; }  // 160 slots, 2048-tok chunks
  float* mlp = (float*)(ws + mlOff);

  k_cvt<<<4096, 256, 0, stream>>>(x, xb, 8192 * 1024);
  k_tcvt<<<dim3(24, 16), 256, 0, stream>>>(w_qkv, wqkvT, 1024, 1536);
  k_tcvt<<<dim3(16, 8), 256, 0, stream>>>(w_out, woutT, 512, 1024);
  k_gemm<<<dim3(12, 64), 256, 0, stream>>>(xb, wqkvT, b_qkv, qkv, nullptr, 8192, 1536, 1024);
  k_tv<<<dim3(8, 128), 256, 0, stream>>>(qkv, vt);
  k_flash5<<<dim3(maxc, 64), 512, 0, stream>>>(qkv, vt, opA, opB, mlp, lgGq, SPLIT);
  k_comb3<<<64, 512, 0, stream>>>(opA, opB, mlp, Ob, lgGq, SPLIT);
  k_gemm<<<dim3(8, 64), 256, 0, stream>>>(Ob, woutT, b_out, nullptr, out, 8192, 1024, 512);
}